// Round 17
// baseline (216.925 us; speedup 1.0000x reference)
//
#include <hip/hip_runtime.h>

#define NUM_DEM 2
#define VOCAB 10000
#define EMB 128
#define NROWS 16384
#define ROWLEN (NUM_DEM + VOCAB)      // 10002
#define KSTEPS 313                    // ceil(10000/32)
#define TILES (KSTEPS + 1)            // +1 zero pad tile (pipeline may stage step 313)
#define NITER 157                     // BK=64 iterations total
#define PCOLS 132                     // partial row stride: 128 pooled + 1 count + pad
#define BPACK_USHORTS ((size_t)TILES * 4096)
#define BPACK_BYTES (BPACK_USHORTS * 2)
#define NCH 4

typedef float f32x4 __attribute__((ext_vector_type(4)));
typedef __bf16 bf16x8 __attribute__((ext_vector_type(8)));
typedef short s16x8 __attribute__((ext_vector_type(8)));

union Frag {
    s16x8 s;
    bf16x8 b;
    unsigned int u[4];
};

__device__ __forceinline__ unsigned short f2bf_rtne(float f) {
    unsigned int u = __float_as_uint(f);
    u += 0x7FFFu + ((u >> 16) & 1u);
    return (unsigned short)(u >> 16);
}

// ---------------- kernel 0: pack embed (fp32 -> bf16 MFMA-B fragment order) ---------
// Bpack[((t*8 + c)*64 + l)*8 + j] = bf16(embed[t*32 + (l>>4)*8 + j][c*16 + (l&15)])
// t == 313 is an all-zero pad tile.
__global__ void pack_embed_k(const float* __restrict__ embed,
                             unsigned short* __restrict__ bp) {
    int id = blockIdx.x * blockDim.x + threadIdx.x;
    if (id >= TILES * 8 * 64) return;
    int l = id & 63;
    int c = (id >> 6) & 7;
    int t = id >> 9;
    int kbase = t * 32 + ((l >> 4) * 8);
    int n = c * 16 + (l & 15);
    unsigned short v[8];
#pragma unroll
    for (int j = 0; j < 8; ++j) {
        int k = kbase + j;
        float f = (k < VOCAB) ? embed[(size_t)k * EMB + n] : 0.0f;
        v[j] = f2bf_rtne(f);
    }
    uint4 w;
    w.x = (unsigned int)v[0] | ((unsigned int)v[1] << 16);
    w.y = (unsigned int)v[2] | ((unsigned int)v[3] << 16);
    w.z = (unsigned int)v[4] | ((unsigned int)v[5] << 16);
    w.w = (unsigned int)v[6] | ((unsigned int)v[7] << 16);
    *reinterpret_cast<uint4*>(bp + (size_t)id * 8) = w;
}

// ---------------- kernel 1: split-K masked-sum GEMM, depth-3 counted-vmcnt ----------
// R16 geometry (512 threads, 8 waves, M=128, BK=64, 2 blocks/CU) with the pipeline
// deepened to distance 3: triple-buffered LDS B (48 KB) + 3 rotating A-slot sets.
// Body m: wait vmcnt(12) (2 bodies in flight); barrier; compute buf/set (m%3);
// barrier; stage B(m+3)+A(m+3) into the just-freed buf/set. Drain: 12,12,6,0.
typedef const __attribute__((address_space(1))) unsigned int* gas_u32p;
typedef __attribute__((address_space(3))) unsigned int* las_u32p;
#define GLOAD_LDS16(g, l)                                                              \
    __builtin_amdgcn_global_load_lds((gas_u32p)(g), (las_u32p)(l), 16, 0, 0)

#define PERM_A(dst, x0, x1)                                                            \
    dst.u[0] = __builtin_amdgcn_perm(__float_as_uint(x0.y), __float_as_uint(x0.x),     \
                                     0x07060302u);                                     \
    dst.u[1] = __builtin_amdgcn_perm(__float_as_uint(x0.w), __float_as_uint(x0.z),     \
                                     0x07060302u);                                     \
    dst.u[2] = __builtin_amdgcn_perm(__float_as_uint(x1.y), __float_as_uint(x1.x),     \
                                     0x07060302u);                                     \
    dst.u[3] = __builtin_amdgcn_perm(__float_as_uint(x1.w), __float_as_uint(x1.z),     \
                                     0x07060302u);

#define WAITVM(N) asm volatile("s_waitcnt vmcnt(" #N ")" ::: "memory")

// stage iter G's two 32-k tiles into LDS buffer BUF: 2 x 16B per thread (512 thr)
#define STAGE_B(G, BUF)                                                                \
    {                                                                                  \
        const unsigned short* gB_ = bp + (size_t)(2 * (G)) * 4096 + tid * 8;           \
        unsigned short* lB_ = &ldsB[BUF][0] + tid * 8;                                 \
        GLOAD_LDS16(gB_, lB_);                                                         \
        GLOAD_LDS16(gB_ + 4096, lB_ + 4096);                                           \
    }

// unconditional clamped A loads for iter G (4 vmem): OOB groups zeroed at consume
#define LOAD_A2(G, A0, A1, A2, A3)                                                     \
    {                                                                                  \
        const int s0_ = 2 * (G), s1_ = s0_ + 1;                                        \
        const f32x4* p0_ = reinterpret_cast<const f32x4*>(                             \
            asrc + ((s0_ * 32 + kgrp8 + 8 <= VOCAB) ? (size_t)(s0_ * 32) : (size_t)0));\
        const f32x4* p1_ = reinterpret_cast<const f32x4*>(                             \
            asrc + ((s1_ * 32 + kgrp8 + 8 <= VOCAB) ? (size_t)(s1_ * 32) : (size_t)0));\
        A0 = p0_[0];                                                                   \
        A1 = p0_[1];                                                                   \
        A2 = p1_[0];                                                                   \
        A3 = p1_[1];                                                                   \
    }

#define BODY(G, BUF, A0, A1, A2, A3, DOPF, N)                                          \
    {                                                                                  \
        WAITVM(N);                                                                     \
        __builtin_amdgcn_s_barrier();                                                  \
        asm volatile("" ::: "memory"); /* pin ds_reads below the barrier */            \
        {                                                                              \
            const int s0_ = 2 * (G), s1_ = s0_ + 1;                                    \
            Frag af0_, af1_;                                                           \
            PERM_A(af0_, A0, A1); /* fp32 0/1 -> bf16 truncation exact */              \
            PERM_A(af1_, A2, A3);                                                      \
            unsigned v0_ = (s0_ * 32 + kgrp8 + 8 <= VOCAB) ? 0xFFFFFFFFu : 0u;         \
            unsigned v1_ = (s1_ * 32 + kgrp8 + 8 <= VOCAB) ? 0xFFFFFFFFu : 0u;         \
            af0_.u[0] &= v0_; af0_.u[1] &= v0_; af0_.u[2] &= v0_; af0_.u[3] &= v0_;    \
            af1_.u[0] &= v1_; af1_.u[1] &= v1_; af1_.u[2] &= v1_; af1_.u[3] &= v1_;    \
            const unsigned short* rB_ = &ldsB[BUF][0] + lane * 8;                      \
            _Pragma("unroll") for (int f = 0; f < 8; ++f) {                            \
                Frag bfr_;                                                             \
                bfr_.s = *reinterpret_cast<const s16x8*>(rB_ + f * 512);               \
                pacc[f] = __builtin_amdgcn_mfma_f32_16x16x32_bf16(af0_.b, bfr_.b,      \
                                                                  pacc[f], 0, 0, 0);   \
            }                                                                          \
            cacc = __builtin_amdgcn_mfma_f32_16x16x32_bf16(af0_.b, onesf.b, cacc, 0,   \
                                                           0, 0);                      \
            _Pragma("unroll") for (int f = 0; f < 8; ++f) {                            \
                Frag bfr_;                                                             \
                bfr_.s = *reinterpret_cast<const s16x8*>(rB_ + 4096 + f * 512);        \
                pacc[f] = __builtin_amdgcn_mfma_f32_16x16x32_bf16(af1_.b, bfr_.b,      \
                                                                  pacc[f], 0, 0, 0);   \
            }                                                                          \
            cacc = __builtin_amdgcn_mfma_f32_16x16x32_bf16(af1_.b, onesf.b, cacc, 0,   \
                                                           0, 0);                      \
        }                                                                              \
        asm volatile("" ::: "memory"); /* pin ds_reads above this barrier */           \
        __builtin_amdgcn_s_barrier();                                                  \
        __builtin_amdgcn_sched_barrier(0);                                             \
        if (DOPF) {                                                                    \
            STAGE_B((G) + 3, BUF);                                                     \
            LOAD_A2((G) + 3, A0, A1, A2, A3);                                          \
        }                                                                              \
    }

__global__ __launch_bounds__(512, 4) void main_gemm_k(
    const float* __restrict__ src, const unsigned short* __restrict__ bp,
    float* __restrict__ part, int nch) {
    __shared__ alignas(16) unsigned short ldsB[3][2 * 4096];  // 48 KB triple buffer

    const int tid = threadIdx.x;
    const int lane = tid & 63;
    const int wid = tid >> 6;        // 0..7
    const int rb = blockIdx.x & 127; // row block: 128 rows
    const int ch = blockIdx.x >> 7;  // K chunk (iter-granular)
    const int I0 = (NITER * ch) / nch;
    const int I1 = (NITER * (ch + 1)) / nch;
    const int nIter = I1 - I0;  // 39 or 40 (nch=4)

    const int rowbase = rb * 128 + wid * 16;
    const int arow = rowbase + (lane & 15);
    const int kgrp8 = (lane >> 4) * 8;
    const float* asrc = src + (size_t)arow * ROWLEN + NUM_DEM + kgrp8;

    f32x4 pacc[8];
#pragma unroll
    for (int f = 0; f < 8; ++f) pacc[f] = (f32x4){0.f, 0.f, 0.f, 0.f};
    f32x4 cacc = (f32x4){0.f, 0.f, 0.f, 0.f};

    Frag onesf;  // B fragment with col 0 == 1.0 (row counts), others 0
    {
        unsigned short o = ((lane & 15) == 0) ? (unsigned short)0x3F80 : (unsigned short)0;
        unsigned int ow = (unsigned int)o | ((unsigned int)o << 16);
        onesf.u[0] = ow; onesf.u[1] = ow; onesf.u[2] = ow; onesf.u[3] = ow;
    }

    // A slot sets, parity-named (rule #20): P, Q, R rotate with period 3
    f32x4 aP0, aP1, aP2, aP3, aQ0, aQ1, aQ2, aQ3, aR0, aR1, aR2, aR3;

    // prologue: bodies I0 -> (buf0,P), I0+1 -> (buf1,Q), I0+2 -> (buf2,R)
    // issue order (fenced): B(0),A(0) | B(1),A(1) | B(2),A(2)  -> 18 outstanding
    STAGE_B(I0, 0);
    LOAD_A2(I0, aP0, aP1, aP2, aP3);
    asm volatile("" ::: "memory");
    STAGE_B(I0 + 1, 1);
    LOAD_A2(I0 + 1, aQ0, aQ1, aQ2, aQ3);
    asm volatile("" ::: "memory");
    STAGE_B(I0 + 2, 2);
    LOAD_A2(I0 + 2, aR0, aR1, aR2, aR3);

    int i = 0;
    for (; i + 5 < nIter; i += 3) {
        BODY(I0 + i,     0, aP0, aP1, aP2, aP3, 1, 12);
        BODY(I0 + i + 1, 1, aQ0, aQ1, aQ2, aQ3, 1, 12);
        BODY(I0 + i + 2, 2, aR0, aR1, aR2, aR3, 1, 12);
    }
    {
        const int r = nIter - i;  // 3, 4, or 5 (i % 3 == 0)
        if (r == 3) {
            BODY(I0 + i,     0, aP0, aP1, aP2, aP3, 0, 12);
            BODY(I0 + i + 1, 1, aQ0, aQ1, aQ2, aQ3, 0, 6);
            BODY(I0 + i + 2, 2, aR0, aR1, aR2, aR3, 0, 0);
        } else if (r == 4) {
            BODY(I0 + i,     0, aP0, aP1, aP2, aP3, 1, 12);
            BODY(I0 + i + 1, 1, aQ0, aQ1, aQ2, aQ3, 0, 12);
            BODY(I0 + i + 2, 2, aR0, aR1, aR2, aR3, 0, 6);
            BODY(I0 + i + 3, 0, aP0, aP1, aP2, aP3, 0, 0);
        } else {  // r == 5
            BODY(I0 + i,     0, aP0, aP1, aP2, aP3, 1, 12);
            BODY(I0 + i + 1, 1, aQ0, aQ1, aQ2, aQ3, 1, 12);
            BODY(I0 + i + 2, 2, aR0, aR1, aR2, aR3, 0, 12);
            BODY(I0 + i + 3, 0, aP0, aP1, aP2, aP3, 0, 6);
            BODY(I0 + i + 4, 1, aQ0, aQ1, aQ2, aQ3, 0, 0);
        }
    }

    // epilogue: C/D layout col = lane&15, row = (lane>>4)*4 + reg
    const int rlo = (lane >> 4) * 4;
    float* pch = part + (size_t)ch * NROWS * PCOLS;
#pragma unroll
    for (int f = 0; f < 8; ++f) {
#pragma unroll
        for (int r = 0; r < 4; ++r) {
            int row = rowbase + rlo + r;
            pch[(size_t)row * PCOLS + f * 16 + (lane & 15)] = pacc[f][r];
        }
    }
    if ((lane & 15) == 0) {
#pragma unroll
        for (int r = 0; r < 4; ++r) {
            int row = rowbase + rlo + r;
            pch[(size_t)row * PCOLS + 128] = cacc[r];
        }
    }
}

// ---------------- kernel 2: reduce partials + MLP ----------------------------------
__global__ __launch_bounds__(256) void mlp_k(const float* __restrict__ part,
                                             const float* __restrict__ src,
                                             const float* __restrict__ W1,
                                             const float* __restrict__ b1,
                                             const float* __restrict__ W2,
                                             const float* __restrict__ b2,
                                             float* __restrict__ out, int nch) {
    __shared__ float xls[16][131];  // [dem(2), pooled(128)] per row
    __shared__ float hls[16][16];
    __shared__ float cnt[16];
    const int tid = threadIdx.x;
    const int rb = blockIdx.x * 16;

    if (tid < 16) {
        float s = 0.f;
        for (int c = 0; c < nch; ++c)
            s += part[((size_t)c * NROWS + rb + tid) * PCOLS + 128];
        cnt[tid] = s;
    }
    if (tid >= 16 && tid < 48) {
        int r = (tid - 16) >> 1, d = (tid - 16) & 1;
        xls[r][d] = src[(size_t)(rb + r) * ROWLEN + d];
    }
    __syncthreads();

    for (int idx = tid; idx < 16 * 128; idx += 256) {
        int r = idx >> 7, col = idx & 127;
        float s = 0.f;
        for (int c = 0; c < nch; ++c)
            s += part[((size_t)c * NROWS + rb + r) * PCOLS + col];
        xls[r][NUM_DEM + col] = s / cnt[r];
    }
    __syncthreads();

    {
        int r = tid >> 4, u = tid & 15;
        float acc = b1[u];
        for (int i = 0; i < NUM_DEM + EMB; ++i) acc += xls[r][i] * W1[i * 16 + u];
        hls[r][u] = tanhf(acc);
    }
    __syncthreads();

    if (tid < 32) {
        int r = tid >> 1, o = tid & 1;
        float acc = b2[o];
#pragma unroll
        for (int u = 0; u < 16; ++u) acc += hls[r][u] * W2[u * 2 + o];
        out[(size_t)(rb + r) * 2 + o] = acc;
    }
}

// ---------------- launch ------------------------------------------------------------
extern "C" void kernel_launch(void* const* d_in, const int* in_sizes, int n_in,
                              void* d_out, int out_size, void* d_ws, size_t ws_size,
                              hipStream_t stream) {
    const float* src = (const float*)d_in[0];
    const float* embed = (const float*)d_in[1];
    const float* W1 = (const float*)d_in[2];
    const float* b1 = (const float*)d_in[3];
    const float* W2 = (const float*)d_in[4];
    const float* b2 = (const float*)d_in[5];
    float* out = (float*)d_out;

    unsigned short* bpack = (unsigned short*)d_ws;
    float* part = (float*)((char*)d_ws + BPACK_BYTES);

    const size_t part1 = (size_t)NROWS * PCOLS * sizeof(float);
    int nch = NCH;
    while (nch > 1 && BPACK_BYTES + part1 * (size_t)nch > ws_size) nch >>= 1;

    hipLaunchKernelGGL(pack_embed_k, dim3((TILES * 8 * 64 + 255) / 256), dim3(256), 0,
                       stream, embed, bpack);
    hipLaunchKernelGGL(main_gemm_k, dim3(128 * nch), dim3(512), 0, stream, src, bpack,
                       part, nch);
    hipLaunchKernelGGL(mlp_k, dim3(NROWS / 16), dim3(256), 0, stream, part, src, W1, b1,
                       W2, b2, out, nch);
}

// Round 18
// 186.559 us; speedup vs baseline: 1.1628x; 1.1628x over previous
//
#include <hip/hip_runtime.h>

#define NUM_DEM 2
#define VOCAB 10000
#define EMB 128
#define NROWS 16384
#define ROWLEN (NUM_DEM + VOCAB)      // 10002
#define KSTEPS 313                    // ceil(10000/32)
#define TILES (KSTEPS + 1)            // +1 zero pad tile (pipeline may stage step 313)
#define NITER 157                     // BK=64 iterations total
#define PCOLS 132                     // partial row stride: 128 pooled + 1 count + pad
#define BPACK_USHORTS ((size_t)TILES * 4096)
#define BPACK_BYTES (BPACK_USHORTS * 2)
#define NCH 4

typedef float f32x4 __attribute__((ext_vector_type(4)));
typedef __bf16 bf16x8 __attribute__((ext_vector_type(8)));
typedef short s16x8 __attribute__((ext_vector_type(8)));

union Frag {
    s16x8 s;
    bf16x8 b;
    unsigned int u[4];
};

__device__ __forceinline__ unsigned short f2bf_rtne(float f) {
    unsigned int u = __float_as_uint(f);
    u += 0x7FFFu + ((u >> 16) & 1u);
    return (unsigned short)(u >> 16);
}

// ---------------- kernel 0: pack embed (fp32 -> bf16 MFMA-B fragment order) ---------
// Bpack[((t*8 + c)*64 + l)*8 + j] = bf16(embed[t*32 + (l>>4)*8 + j][c*16 + (l&15)])
// t == 313 is an all-zero pad tile.
__global__ void pack_embed_k(const float* __restrict__ embed,
                             unsigned short* __restrict__ bp) {
    int id = blockIdx.x * blockDim.x + threadIdx.x;
    if (id >= TILES * 8 * 64) return;
    int l = id & 63;
    int c = (id >> 6) & 7;
    int t = id >> 9;
    int kbase = t * 32 + ((l >> 4) * 8);
    int n = c * 16 + (l & 15);
    unsigned short v[8];
#pragma unroll
    for (int j = 0; j < 8; ++j) {
        int k = kbase + j;
        float f = (k < VOCAB) ? embed[(size_t)k * EMB + n] : 0.0f;
        v[j] = f2bf_rtne(f);
    }
    uint4 w;
    w.x = (unsigned int)v[0] | ((unsigned int)v[1] << 16);
    w.y = (unsigned int)v[2] | ((unsigned int)v[3] << 16);
    w.z = (unsigned int)v[4] | ((unsigned int)v[5] << 16);
    w.w = (unsigned int)v[6] | ((unsigned int)v[7] << 16);
    *reinterpret_cast<uint4*>(bp + (size_t)id * 8) = w;
}

// ---------------- kernel 1: split-K masked-sum GEMM, M=128 + counted-vmcnt ----------
// R16 (champion, 184.3us) with ONE reorder: the A(i+2) register loads are issued
// MID-BODY (right after the perms consume the old slot values), not after the
// second barrier. A needs no LDS/barrier protection, so this adds ~1 MFMA-cluster
// of latency slack for the HBM A-stream at zero VGPR/LDS cost. B staging stays
// post-barrier (same-buffer race otherwise). vmcnt counts unchanged:
// steady queue = A(m)4,B(m)2,A(m+1)4,B(m+1)2 = 12 -> wait(6) retires A(m),B(m).
typedef const __attribute__((address_space(1))) unsigned int* gas_u32p;
typedef __attribute__((address_space(3))) unsigned int* las_u32p;
#define GLOAD_LDS16(g, l)                                                              \
    __builtin_amdgcn_global_load_lds((gas_u32p)(g), (las_u32p)(l), 16, 0, 0)

#define PERM_A(dst, x0, x1)                                                            \
    dst.u[0] = __builtin_amdgcn_perm(__float_as_uint(x0.y), __float_as_uint(x0.x),     \
                                     0x07060302u);                                     \
    dst.u[1] = __builtin_amdgcn_perm(__float_as_uint(x0.w), __float_as_uint(x0.z),     \
                                     0x07060302u);                                     \
    dst.u[2] = __builtin_amdgcn_perm(__float_as_uint(x1.y), __float_as_uint(x1.x),     \
                                     0x07060302u);                                     \
    dst.u[3] = __builtin_amdgcn_perm(__float_as_uint(x1.w), __float_as_uint(x1.z),     \
                                     0x07060302u);

#define WAITVM(N) asm volatile("s_waitcnt vmcnt(" #N ")" ::: "memory")

// stage iter G's two 32-k tiles into LDS buffer BUF: 2 x 16B per thread (512 thr)
#define STAGE_B(G, BUF)                                                                \
    {                                                                                  \
        const unsigned short* gB_ = bp + (size_t)(2 * (G)) * 4096 + tid * 8;           \
        unsigned short* lB_ = &ldsB[BUF][0] + tid * 8;                                 \
        GLOAD_LDS16(gB_, lB_);                                                         \
        GLOAD_LDS16(gB_ + 4096, lB_ + 4096);                                           \
    }

// unconditional clamped A loads for iter G (4 vmem): OOB groups zeroed at consume
#define LOAD_A2(G, A0, A1, A2, A3)                                                     \
    {                                                                                  \
        const int s0_ = 2 * (G), s1_ = s0_ + 1;                                        \
        const f32x4* p0_ = reinterpret_cast<const f32x4*>(                             \
            asrc + ((s0_ * 32 + kgrp8 + 8 <= VOCAB) ? (size_t)(s0_ * 32) : (size_t)0));\
        const f32x4* p1_ = reinterpret_cast<const f32x4*>(                             \
            asrc + ((s1_ * 32 + kgrp8 + 8 <= VOCAB) ? (size_t)(s1_ * 32) : (size_t)0));\
        A0 = p0_[0];                                                                   \
        A1 = p0_[1];                                                                   \
        A2 = p1_[0];                                                                   \
        A3 = p1_[1];                                                                   \
    }

#define BODY(G, BUF, A0, A1, A2, A3, DOPF, PFG, N)                                     \
    {                                                                                  \
        WAITVM(N);                                                                     \
        __builtin_amdgcn_s_barrier();                                                  \
        asm volatile("" ::: "memory"); /* pin ds_reads below the barrier */            \
        {                                                                              \
            const int s0_ = 2 * (G), s1_ = s0_ + 1;                                    \
            Frag af0_, af1_;                                                           \
            PERM_A(af0_, A0, A1); /* fp32 0/1 -> bf16 truncation exact */              \
            PERM_A(af1_, A2, A3);                                                      \
            unsigned v0_ = (s0_ * 32 + kgrp8 + 8 <= VOCAB) ? 0xFFFFFFFFu : 0u;         \
            unsigned v1_ = (s1_ * 32 + kgrp8 + 8 <= VOCAB) ? 0xFFFFFFFFu : 0u;         \
            af0_.u[0] &= v0_; af0_.u[1] &= v0_; af0_.u[2] &= v0_; af0_.u[3] &= v0_;    \
            af1_.u[0] &= v1_; af1_.u[1] &= v1_; af1_.u[2] &= v1_; af1_.u[3] &= v1_;    \
            asm volatile("" ::: "memory");                                             \
            if (DOPF) { LOAD_A2(PFG, A0, A1, A2, A3); } /* A issued early (regs) */    \
            asm volatile("" ::: "memory");                                             \
            const unsigned short* rB_ = &ldsB[BUF][0] + lane * 8;                      \
            _Pragma("unroll") for (int f = 0; f < 8; ++f) {                            \
                Frag bfr_;                                                             \
                bfr_.s = *reinterpret_cast<const s16x8*>(rB_ + f * 512);               \
                pacc[f] = __builtin_amdgcn_mfma_f32_16x16x32_bf16(af0_.b, bfr_.b,      \
                                                                  pacc[f], 0, 0, 0);   \
            }                                                                          \
            cacc = __builtin_amdgcn_mfma_f32_16x16x32_bf16(af0_.b, onesf.b, cacc, 0,   \
                                                           0, 0);                      \
            _Pragma("unroll") for (int f = 0; f < 8; ++f) {                            \
                Frag bfr_;                                                             \
                bfr_.s = *reinterpret_cast<const s16x8*>(rB_ + 4096 + f * 512);        \
                pacc[f] = __builtin_amdgcn_mfma_f32_16x16x32_bf16(af1_.b, bfr_.b,      \
                                                                  pacc[f], 0, 0, 0);   \
            }                                                                          \
            cacc = __builtin_amdgcn_mfma_f32_16x16x32_bf16(af1_.b, onesf.b, cacc, 0,   \
                                                           0, 0);                      \
        }                                                                              \
        asm volatile("" ::: "memory"); /* pin ds_reads above this barrier */           \
        __builtin_amdgcn_s_barrier();                                                  \
        __builtin_amdgcn_sched_barrier(0);                                             \
        if (DOPF) { STAGE_B(PFG, BUF); } /* B staged after barrier (LDS safety) */     \
    }

__global__ __launch_bounds__(512, 4) void main_gemm_k(
    const float* __restrict__ src, const unsigned short* __restrict__ bp,
    float* __restrict__ part, int nch) {
    __shared__ alignas(16) unsigned short ldsB[2][2 * 4096];  // 32 KB double buffer

    const int tid = threadIdx.x;
    const int lane = tid & 63;
    const int wid = tid >> 6;        // 0..7
    const int rb = blockIdx.x & 127; // row block: 128 rows
    const int ch = blockIdx.x >> 7;  // K chunk (iter-granular)
    const int I0 = (NITER * ch) / NCH;
    const int I1 = (NITER * (ch + 1)) / NCH;
    const int nIter = I1 - I0;  // 39 or 40

    const int rowbase = rb * 128 + wid * 16;
    const int arow = rowbase + (lane & 15);
    const int kgrp8 = (lane >> 4) * 8;
    const float* asrc = src + (size_t)arow * ROWLEN + NUM_DEM + kgrp8;

    f32x4 pacc[8];
#pragma unroll
    for (int f = 0; f < 8; ++f) pacc[f] = (f32x4){0.f, 0.f, 0.f, 0.f};
    f32x4 cacc = (f32x4){0.f, 0.f, 0.f, 0.f};

    Frag onesf;  // B fragment with col 0 == 1.0 (row counts), others 0
    {
        unsigned short o = ((lane & 15) == 0) ? (unsigned short)0x3F80 : (unsigned short)0;
        unsigned int ow = (unsigned int)o | ((unsigned int)o << 16);
        onesf.u[0] = ow; onesf.u[1] = ow; onesf.u[2] = ow; onesf.u[3] = ow;
    }

    f32x4 aP0, aP1, aP2, aP3, aQ0, aQ1, aQ2, aQ3;  // A slots, parity-named (rule #20)

    // prologue: iters I0 -> buf0/P, I0+1 -> buf1/Q (groups fenced for vmcnt order)
    STAGE_B(I0, 0);
    LOAD_A2(I0, aP0, aP1, aP2, aP3);
    asm volatile("" ::: "memory");
    STAGE_B(I0 + 1, 1);
    LOAD_A2(I0 + 1, aQ0, aQ1, aQ2, aQ3);
    // outstanding: B(0)+A(0) = 6, B(1)+A(1) = 6 -> steady-state wait = vmcnt(6)

    int i = 0;
    for (; i + 3 < nIter; i += 2) {
        BODY(I0 + i, 0, aP0, aP1, aP2, aP3, 1, I0 + i + 2, 6);
        BODY(I0 + i + 1, 1, aQ0, aQ1, aQ2, aQ3, 1, I0 + i + 3, 6);
    }
    if (nIter - i == 3) {
        BODY(I0 + i, 0, aP0, aP1, aP2, aP3, 1, I0 + i + 2, 6);
        BODY(I0 + i + 1, 1, aQ0, aQ1, aQ2, aQ3, 0, 0, 6);
        BODY(I0 + i + 2, 0, aP0, aP1, aP2, aP3, 0, 0, 0);
    } else {  // nIter - i == 2
        BODY(I0 + i, 0, aP0, aP1, aP2, aP3, 0, 0, 6);
        BODY(I0 + i + 1, 1, aQ0, aQ1, aQ2, aQ3, 0, 0, 0);
    }

    // epilogue: C/D layout col = lane&15, row = (lane>>4)*4 + reg
    const int rlo = (lane >> 4) * 4;
    float* pch = part + (size_t)ch * NROWS * PCOLS;
#pragma unroll
    for (int f = 0; f < 8; ++f) {
#pragma unroll
        for (int r = 0; r < 4; ++r) {
            int row = rowbase + rlo + r;
            pch[(size_t)row * PCOLS + f * 16 + (lane & 15)] = pacc[f][r];
        }
    }
    if ((lane & 15) == 0) {
#pragma unroll
        for (int r = 0; r < 4; ++r) {
            int row = rowbase + rlo + r;
            pch[(size_t)row * PCOLS + 128] = cacc[r];
        }
    }
}

// ---------------- kernel 2: reduce partials + MLP ----------------------------------
__global__ __launch_bounds__(256) void mlp_k(const float* __restrict__ part,
                                             const float* __restrict__ src,
                                             const float* __restrict__ W1,
                                             const float* __restrict__ b1,
                                             const float* __restrict__ W2,
                                             const float* __restrict__ b2,
                                             float* __restrict__ out, int nch) {
    __shared__ float xls[16][131];  // [dem(2), pooled(128)] per row
    __shared__ float hls[16][16];
    __shared__ float cnt[16];
    const int tid = threadIdx.x;
    const int rb = blockIdx.x * 16;

    if (tid < 16) {
        float s = 0.f;
        for (int c = 0; c < nch; ++c)
            s += part[((size_t)c * NROWS + rb + tid) * PCOLS + 128];
        cnt[tid] = s;
    }
    if (tid >= 16 && tid < 48) {
        int r = (tid - 16) >> 1, d = (tid - 16) & 1;
        xls[r][d] = src[(size_t)(rb + r) * ROWLEN + d];
    }
    __syncthreads();

    for (int idx = tid; idx < 16 * 128; idx += 256) {
        int r = idx >> 7, col = idx & 127;
        float s = 0.f;
        for (int c = 0; c < nch; ++c)
            s += part[((size_t)c * NROWS + rb + r) * PCOLS + col];
        xls[r][NUM_DEM + col] = s / cnt[r];
    }
    __syncthreads();

    {
        int r = tid >> 4, u = tid & 15;
        float acc = b1[u];
        for (int i = 0; i < NUM_DEM + EMB; ++i) acc += xls[r][i] * W1[i * 16 + u];
        hls[r][u] = tanhf(acc);
    }
    __syncthreads();

    if (tid < 32) {
        int r = tid >> 1, o = tid & 1;
        float acc = b2[o];
#pragma unroll
        for (int u = 0; u < 16; ++u) acc += hls[r][u] * W2[u * 2 + o];
        out[(size_t)(rb + r) * 2 + o] = acc;
    }
}

// ---------------- launch ------------------------------------------------------------
extern "C" void kernel_launch(void* const* d_in, const int* in_sizes, int n_in,
                              void* d_out, int out_size, void* d_ws, size_t ws_size,
                              hipStream_t stream) {
    const float* src = (const float*)d_in[0];
    const float* embed = (const float*)d_in[1];
    const float* W1 = (const float*)d_in[2];
    const float* b1 = (const float*)d_in[3];
    const float* W2 = (const float*)d_in[4];
    const float* b2 = (const float*)d_in[5];
    float* out = (float*)d_out;

    unsigned short* bpack = (unsigned short*)d_ws;
    float* part = (float*)((char*)d_ws + BPACK_BYTES);

    hipLaunchKernelGGL(pack_embed_k, dim3((TILES * 8 * 64 + 255) / 256), dim3(256), 0,
                       stream, embed, bpack);
    hipLaunchKernelGGL(main_gemm_k, dim3(128 * NCH), dim3(512), 0, stream, src, bpack,
                       part, NCH);
    hipLaunchKernelGGL(mlp_k, dim3(NROWS / 16), dim3(256), 0, stream, part, src, W1, b1,
                       W2, b2, out, NCH);
}